// Round 4
// baseline (733.721 us; speedup 1.0000x reference)
//
#include <hip/hip_runtime.h>
#include <stdint.h>

#define B_ 1024
#define Q_ 65536
#define D_ 512
#define MT 128
#define NT 128
#define BK 64
#define NSPLIT 64
#define NCHUNK (Q_ / NSPLIT)   // 1024
#define NTILES (NCHUNK / NT)   // 8
#define KITERS (D_ / BK)       // 8

#define SCALE32 32.0f
#define C32 46.16624130844683f   // 32 * log2(e)

// ---- workspace layout (bytes) ----
// [0,16)   : ce_acc f32 | neg_acc f32 | npos i32 | nneg i32
// [4 KB)   : LSE partials float2(Z_mat0, Z_mat1), idx row*64+split  (512 KB)
// [1 MB)   : top-10 partials, idx ((mat*B+row)*64+split)*10         (5.24 MB)
// [8 MB)   : p bf16 (1 MB)
// [12 MB)  : queue[0] bf16 (64 MB)
// [76 MB)  : w = m*q1+(1-m)*q0 bf16 (64 MB)  -> total 140 MB
#define WS_ACC  0
#define WS_LSE  4096
#define WS_TOPK (1u * 1024u * 1024u)
#define WS_PBF  (8u * 1024u * 1024u)
#define WS_QBF0 (12u * 1024u * 1024u)
#define WS_WBF  (76u * 1024u * 1024u)

// ---- LDS: staging sA[0,16K) sB0[16K,32K) sB1[32K,48K); 16B-XOR swizzle.
// topk compact (2 mats x 32 rows x 128 cols bf16 = 16 KB) aliases sA,
// barrier-separated from staging use.
#define SA_OFF 0
#define SB0_OFF 16384
#define SB1_OFF 32768

typedef __attribute__((ext_vector_type(8))) short short8;
typedef __attribute__((ext_vector_type(4))) short short4v;
typedef __attribute__((ext_vector_type(4))) float f32x4;

__device__ __forceinline__ unsigned short f2bf(float x) {
  union { float f; uint32_t u; } v; v.f = x;
  uint32_t r = v.u + 0x7fffu + ((v.u >> 16) & 1u);   // RNE
  return (unsigned short)(r >> 16);
}

__device__ __forceinline__ float bf2f(short u) {
  union { uint32_t i; float f; } v;
  v.i = ((uint32_t)(unsigned short)u) << 16;
  return v.f;
}

__device__ __forceinline__ void async16(void* lds, const void* g) {
  void* gg = (void*)g;
  __builtin_amdgcn_global_load_lds(
      (__attribute__((address_space(1))) unsigned int*)gg,
      (__attribute__((address_space(3))) unsigned int*)lds,
      16, 0, 0);
}

__device__ __forceinline__ void tkins(float v,
    float& t0, float& t1, float& t2, float& t3, float& t4,
    float& t5, float& t6, float& t7, float& t8, float& t9) {
  if (v > t9) {
    t9 = (v > t8) ? t8 : v;
    t8 = (v > t8) ? ((v > t7) ? t7 : v) : t8;
    t7 = (v > t7) ? ((v > t6) ? t6 : v) : t7;
    t6 = (v > t6) ? ((v > t5) ? t5 : v) : t6;
    t5 = (v > t5) ? ((v > t4) ? t4 : v) : t5;
    t4 = (v > t4) ? ((v > t3) ? t3 : v) : t4;
    t3 = (v > t3) ? ((v > t2) ? t2 : v) : t3;
    t2 = (v > t2) ? ((v > t1) ? t1 : v) : t2;
    t1 = (v > t1) ? ((v > t0) ? t0 : v) : t1;
    t0 = (v > t0) ? v : t0;
  }
}

#define TKA(v, a) tkins((v), a[0], a[1], a[2], a[3], a[4], a[5], a[6], a[7], a[8], a[9])

// fused converter: queue fp32 -> {qbf0, wbf} (blocks < Q_/4), p -> pbf (rest)
__global__ void cvt_all(const float* __restrict__ q, const float* __restrict__ p,
                        const float* __restrict__ mask,
                        unsigned short* __restrict__ qbf0,
                        unsigned short* __restrict__ wbf,
                        unsigned short* __restrict__ pbf) {
  const int wv = threadIdx.x >> 6;
  const int lane = threadIdx.x & 63;
  const int b = blockIdx.x;
  if (b < Q_ / 4) {
    const int row = b * 4 + wv;
    const float* q0r = q + (size_t)row * D_ + lane * 8;
    float4 a = ((const float4*)q0r)[0];
    float4 bb = ((const float4*)q0r)[1];
    short8 o;
    o[0] = (short)f2bf(a.x); o[1] = (short)f2bf(a.y);
    o[2] = (short)f2bf(a.z); o[3] = (short)f2bf(a.w);
    o[4] = (short)f2bf(bb.x); o[5] = (short)f2bf(bb.y);
    o[6] = (short)f2bf(bb.z); o[7] = (short)f2bf(bb.w);
    *(short8*)(qbf0 + (size_t)row * D_ + lane * 8) = o;
    float m = mask[row];
    if (m != 0.0f) {      // wave-uniform
      const float* q1r = q0r + (size_t)Q_ * D_;
      float4 c = ((const float4*)q1r)[0];
      float4 d = ((const float4*)q1r)[1];
      a.x = fmaf(m, c.x - a.x, a.x); a.y = fmaf(m, c.y - a.y, a.y);
      a.z = fmaf(m, c.z - a.z, a.z); a.w = fmaf(m, c.w - a.w, a.w);
      bb.x = fmaf(m, d.x - bb.x, bb.x); bb.y = fmaf(m, d.y - bb.y, bb.y);
      bb.z = fmaf(m, d.z - bb.z, bb.z); bb.w = fmaf(m, d.w - bb.w, bb.w);
      o[0] = (short)f2bf(a.x); o[1] = (short)f2bf(a.y);
      o[2] = (short)f2bf(a.z); o[3] = (short)f2bf(a.w);
      o[4] = (short)f2bf(bb.x); o[5] = (short)f2bf(bb.y);
      o[6] = (short)f2bf(bb.z); o[7] = (short)f2bf(bb.w);
    }
    *(short8*)(wbf + (size_t)row * D_ + lane * 8) = o;
  } else {
    const int row = (b - Q_ / 4) * 4 + wv;
    const float* pr = p + (size_t)row * D_ + lane * 8;
    float4 a = ((const float4*)pr)[0];
    float4 bb = ((const float4*)pr)[1];
    short8 o;
    o[0] = (short)f2bf(a.x); o[1] = (short)f2bf(a.y);
    o[2] = (short)f2bf(a.z); o[3] = (short)f2bf(a.w);
    o[4] = (short)f2bf(bb.x); o[5] = (short)f2bf(bb.y);
    o[6] = (short)f2bf(bb.z); o[7] = (short)f2bf(bb.w);
    *(short8*)(pbf + (size_t)row * D_ + lane * 8) = o;
  }
}

// grid (NSPLIT, 8): x=split -> all 16 blocks of an XCD's split set co-resident
// AND all 512 blocks resident (2 blocks/CU). Dual-GEMM per block; epilogue
// is register-resident (fixed M=32 logsumexp), no LDS tile round-trip.
__global__ __launch_bounds__(256, 2) void fused_gemm_partial(
    const unsigned short* __restrict__ pbf,
    const unsigned short* __restrict__ qbf0,
    const unsigned short* __restrict__ wbf,
    const float* __restrict__ maskp,
    const int* __restrict__ label,
    char* __restrict__ ws) {
  __shared__ __align__(16) unsigned char smem[49152];
  __shared__ float maskbuf[NT];
  __shared__ float zbuf[MT][4];
  __shared__ int olist[MT];
  __shared__ int rowmap[MT];
  __shared__ int sh_ocount;

  const int tid = threadIdx.x;
  const int split = blockIdx.x;       // 0..63
  const int mblk = blockIdx.y;        // 0..7
  const int lane = tid & 63;
  const int wv = tid >> 6;
  const int wr = wv >> 1;
  const int wc = wv & 1;
  const int lr = lane & 15;
  const int lg = lane >> 4;

  if (tid == 0) sh_ocount = 0;
  if (tid < MT) rowmap[tid] = -1;
  __syncthreads();
  if (tid < MT) {
    if (label[mblk * MT + tid] == -1) {
      int k = atomicAdd(&sh_ocount, 1);
      olist[k] = tid;
    }
  }
  __syncthreads();
  const int noc = sh_ocount;
  if (tid < noc) rowmap[olist[tid]] = tid;
  __syncthreads();
  const int nchunks = (noc + 31) >> 5;

  // staging lane constants: lane covers row slot*8+(lane>>3),
  // swizzled col16 = (lane&7) ^ (row&7)
  const int srow = lane >> 3;
  const int sc16 = (lane & 7) ^ srow;
  const size_t g_lane_off = (size_t)srow * D_ + sc16 * 8;

  // per-lane state: Z sums (fixed max M=32) and owner top-10 list
  float z0s[16], z1s[16];
#pragma unroll
  for (int i = 0; i < 16; ++i) { z0s[i] = 0.0f; z1s[i] = 0.0f; }
  float T[10];
#pragma unroll
  for (int i = 0; i < 10; ++i) T[i] = -1e30f;

  for (int nt = 0; nt < NTILES; ++nt) {
    const int nbase = split * NCHUNK + nt * NT;
    if (tid < NT) maskbuf[tid] = maskp[nbase + tid];

    f32x4 acc0[4][4], acc1[4][4];
#pragma unroll
    for (int i = 0; i < 4; ++i)
#pragma unroll
      for (int j = 0; j < 4; ++j) {
        f32x4 z = {0.0f, 0.0f, 0.0f, 0.0f};
        acc0[i][j] = z;
        acc1[i][j] = z;
      }

    for (int kk = 0; kk < KITERS; ++kk) {
      const size_t kcol = (size_t)kk * BK;
#pragma unroll
      for (int t = 0; t < 4; ++t) {
        const int slot = wv * 4 + t;
        const size_t rbase = (size_t)slot * 8;
        async16(smem + SA_OFF + slot * 1024,
                pbf + ((size_t)mblk * MT + rbase) * D_ + kcol + g_lane_off);
        async16(smem + SB0_OFF + slot * 1024,
                qbf0 + ((size_t)nbase + rbase) * D_ + kcol + g_lane_off);
        async16(smem + SB1_OFF + slot * 1024,
                wbf + ((size_t)nbase + rbase) * D_ + kcol + g_lane_off);
      }
      __syncthreads();

#pragma unroll
      for (int s = 0; s < 2; ++s) {
        const int xs = ((s * 4 + lg) ^ (lr & 7)) * 16;
        short8 af[4], bf[4];
#pragma unroll
        for (int i = 0; i < 4; ++i)
          af[i] = *(const short8*)(smem + SA_OFF + (wr * 64 + i * 16 + lr) * 128 + xs);
#pragma unroll
        for (int j = 0; j < 4; ++j)
          bf[j] = *(const short8*)(smem + SB0_OFF + (wc * 64 + j * 16 + lr) * 128 + xs);
#pragma unroll
        for (int i = 0; i < 4; ++i)
#pragma unroll
          for (int j = 0; j < 4; ++j)
            acc0[i][j] = __builtin_amdgcn_mfma_f32_16x16x32_bf16(af[i], bf[j], acc0[i][j], 0, 0, 0);
#pragma unroll
        for (int j = 0; j < 4; ++j)
          bf[j] = *(const short8*)(smem + SB1_OFF + (wc * 64 + j * 16 + lr) * 128 + xs);
#pragma unroll
        for (int i = 0; i < 4; ++i)
#pragma unroll
          for (int j = 0; j < 4; ++j)
            acc1[i][j] = __builtin_amdgcn_mfma_f32_16x16x32_bf16(af[i], bf[j], acc1[i][j], 0, 0, 0);
      }
      __syncthreads();
    }

    // ---- register epilogue: Z accumulation (no LDS, no barrier) ----
    float mcol[4];
#pragma unroll
    for (int j = 0; j < 4; ++j) mcol[j] = maskbuf[wc * 64 + j * 16 + lr];
#pragma unroll
    for (int i = 0; i < 4; ++i)
#pragma unroll
      for (int k = 0; k < 4; ++k) {
        float a0 = 0.0f, a1 = 0.0f;
#pragma unroll
        for (int j = 0; j < 4; ++j) {
          float g0 = acc0[i][j][k];
          float g2 = fmaf(mcol[j], acc1[i][j][k] - g0, g0);
          a0 += __builtin_amdgcn_exp2f(fmaf(g0, C32, -C32));
          a1 += __builtin_amdgcn_exp2f(fmaf(g2, C32, -C32));
        }
        z0s[i * 4 + k] += a0;
        z1s[i * 4 + k] += a1;
      }

    // ---- top-10 for outlier rows: compact -> scan -> register/RMW merge ----
    for (int c = 0; c < nchunks; ++c) {
      unsigned short* cp = (unsigned short*)smem;   // aliases sA (16 KB)
#pragma unroll
      for (int i = 0; i < 4; ++i)
#pragma unroll
        for (int k = 0; k < 4; ++k) {
          const int r = wr * 64 + i * 16 + lg * 4 + k;
          const int o_ = rowmap[r] - c * 32;
          if (o_ >= 0 && o_ < 32 && rowmap[r] >= 0) {
#pragma unroll
            for (int j = 0; j < 4; ++j) {
              const int col = wc * 64 + j * 16 + lr;
              float g0 = acc0[i][j][k];
              float g2 = fmaf(mcol[j], acc1[i][j][k] - g0, g0);
              cp[o_ * 128 + col] = f2bf(g0);
              cp[(32 + o_) * 128 + col] = f2bf(g2);
            }
          }
        }
      __syncthreads();

      {
        float tl[10];
#pragma unroll
        for (int r = 0; r < 10; ++r) tl[r] = -1e30f;
        const int u = wv * 16 + (lane >> 2);
        const int q4 = lane & 3;
        const int o_l = u >> 1, mat = u & 1;
        const int o = c * 32 + o_l;
        if (o < noc) {
          const unsigned short* rp = cp + (mat * 32 + o_l) * 128 + q4 * 32;
#pragma unroll
          for (int cc = 0; cc < 8; ++cc) {
            short4v v = *(const short4v*)(rp + cc * 4);
            TKA(bf2f(v.x), tl); TKA(bf2f(v.y), tl);
            TKA(bf2f(v.z), tl); TKA(bf2f(v.w), tl);
          }
        }
        // merge sorted lists across the 4 quarter-threads (same wave)
        {
          float ot[10];
#pragma unroll
          for (int r = 0; r < 10; ++r) ot[r] = __shfl_xor(tl[r], 1, 64);
#pragma unroll
          for (int r = 0; r < 10; ++r) TKA(ot[r], tl);
#pragma unroll
          for (int r = 0; r < 10; ++r) ot[r] = __shfl_xor(tl[r], 2, 64);
#pragma unroll
          for (int r = 0; r < 10; ++r) TKA(ot[r], tl);
        }
        if (q4 == 0 && o < noc) {
          if (o < 32) {
#pragma unroll
            for (int r = 0; r < 10; ++r) TKA(tl[r], T);
          } else {
            // rare overflow path (noc > 32): owner RMWs its ws slot per nt
            float* slot = (float*)(ws + WS_TOPK) +
                ((size_t)(mat * B_ + mblk * MT + olist[o]) * NSPLIT + split) * 10;
            if (nt == 0) {
#pragma unroll
              for (int r = 0; r < 10; ++r) slot[r] = tl[r];
            } else {
              float cur[10];
#pragma unroll
              for (int r = 0; r < 10; ++r) cur[r] = slot[r];
#pragma unroll
              for (int r = 0; r < 10; ++r) TKA(tl[r], cur);
#pragma unroll
              for (int r = 0; r < 10; ++r) slot[r] = cur[r];
            }
          }
        }
      }
      __syncthreads();
    }
  }

  // ---- block end: merge Z over the 16 lr-lanes, combine wc halves, write ----
#pragma unroll
  for (int i = 0; i < 4; ++i)
#pragma unroll
    for (int k = 0; k < 4; ++k) {
      float z0 = z0s[i * 4 + k], z1 = z1s[i * 4 + k];
#pragma unroll
      for (int m = 1; m < 16; m <<= 1) {
        z0 += __shfl_xor(z0, m, 64);
        z1 += __shfl_xor(z1, m, 64);
      }
      if (lr == 0) {
        const int r = wr * 64 + i * 16 + lg * 4 + k;
        zbuf[r][wc * 2 + 0] = z0;
        zbuf[r][wc * 2 + 1] = z1;
      }
    }
  __syncthreads();
  if (tid < MT) {
    float2* lseo = (float2*)(ws + WS_LSE);
    lseo[(size_t)(mblk * MT + tid) * NSPLIT + split] =
        make_float2(zbuf[tid][0] + zbuf[tid][2], zbuf[tid][1] + zbuf[tid][3]);
  }
  if ((lane & 3) == 0) {
    const int u = wv * 16 + (lane >> 2);
    const int o = u >> 1, mat = u & 1;
    if (o < noc && o < 32) {
      float* slot = (float*)(ws + WS_TOPK) +
          ((size_t)(mat * B_ + mblk * MT + olist[o]) * NSPLIT + split) * 10;
#pragma unroll
      for (int r = 0; r < 10; ++r) slot[r] = T[r];
    }
  }
}

__global__ void finalize_rows(
    const float* __restrict__ p, const float* __restrict__ queue,
    const float* __restrict__ maskp, const int* __restrict__ label,
    char* __restrict__ ws) {
  const int row = blockIdx.x;
  const int l = threadIdx.x >> 6;     // 0: cos1 loss, 1: cos2 loss
  const int lane = threadIdx.x & 63;
  const int lab = label[row];
  float* wsf = (float*)ws;
  int* wsi = (int*)ws;

  if (lab != -1) {
    // ---- sum 64 split Z partials (fixed M=32) ----
    const float2* lsep = (const float2*)(ws + WS_LSE) + (size_t)row * NSPLIT;
    float2 zz = lsep[lane];
    float z = (l == 0) ? zz.x : zz.y;
#pragma unroll
    for (int o = 1; o < 64; o <<= 1) z += __shfl_xor(z, o, 64);

    // ---- exact fp32 gt dot(s) ----
    const float* prow = p + (size_t)row * D_;
    const float* q0r = queue + (size_t)lab * D_;
    const float* q1r = queue + ((size_t)Q_ + (size_t)lab) * D_;
    int c = lane * 8;
    float4 a0 = *(const float4*)(prow + c);
    float4 a1 = *(const float4*)(prow + c + 4);
    float4 b0 = *(const float4*)(q0r + c);
    float4 b1 = *(const float4*)(q0r + c + 4);
    float d0 = a0.x * b0.x + a0.y * b0.y + a0.z * b0.z + a0.w * b0.w
             + a1.x * b1.x + a1.y * b1.y + a1.z * b1.z + a1.w * b1.w;
    float d1 = 0.0f;
    if (l == 1) {
      float4 c0 = *(const float4*)(q1r + c);
      float4 c1 = *(const float4*)(q1r + c + 4);
      d1 = a0.x * c0.x + a0.y * c0.y + a0.z * c0.z + a0.w * c0.w
         + a1.x * c1.x + a1.y * c1.y + a1.z * c1.z + a1.w * c1.w;
    }
#pragma unroll
    for (int o = 1; o < 64; o <<= 1) {
      d0 += __shfl_xor(d0, o, 64);
      d1 += __shfl_xor(d1, o, 64);
    }
    float gt;
    if (l == 0) gt = d0;
    else { float m = maskp[lab]; gt = fmaf(m, d1 - d0, d0); }

    if (lane == 0) {
      float e1 = __builtin_amdgcn_exp2f(fmaf(gt, C32, -C32));
      float e2 = __builtin_amdgcn_exp2f(fmaf(gt - 0.4f, C32, -C32));
      float Zc = z - e1 + e2;
      float ce = 32.0f + __logf(Zc) - (gt - 0.4f) * SCALE32;
      atomicAdd(&wsf[0], ce);
      if (l == 0) atomicAdd(&wsi[2], 1);
    }
  } else {
    // ---- merge 64 sorted top-10 lists: 10-round wave tournament ----
    const float* tp = (const float*)(ws + WS_TOPK) +
                      ((size_t)l * B_ + row) * NSPLIT * 10 + (size_t)lane * 10;
    float t0 = tp[0], t1 = tp[1], t2 = tp[2], t3 = tp[3], t4 = tp[4];
    float t5 = tp[5], t6 = tp[6], t7 = tp[7], t8 = tp[8], t9 = tp[9];
    float ssum = 0.0f;
#pragma unroll
    for (int r10 = 0; r10 < 10; ++r10) {
      float v = t0;
      int idx = lane;
#pragma unroll
      for (int o = 1; o < 64; o <<= 1) {
        float ov = __shfl_xor(v, o, 64);
        int oi = __shfl_xor(idx, o, 64);
        bool take = (ov > v) || (ov == v && oi < idx);
        v = take ? ov : v;
        idx = take ? oi : idx;
      }
      ssum += fmaxf(v, 0.0f);
      if (idx == lane) {
        t0 = t1; t1 = t2; t2 = t3; t3 = t4; t4 = t5;
        t5 = t6; t6 = t7; t7 = t8; t8 = t9; t9 = -1e30f;
      }
    }
    if (lane == 0) {
      atomicAdd(&wsf[1], ssum * 0.1f);
      if (l == 0) atomicAdd(&wsi[3], 1);
    }
  }
}

__global__ void finalize_scalar(const char* __restrict__ ws, float* __restrict__ out) {
  const float* wsf = (const float*)ws;
  const int* wsi = (const int*)ws;
  float loss = 0.0f;
  if (wsi[2] > 0) loss += wsf[0] / (float)wsi[2];
  if (wsi[3] > 0) loss += wsf[1] / (float)wsi[3];
  out[0] = loss;
}

extern "C" void kernel_launch(void* const* d_in, const int* in_sizes, int n_in,
                              void* d_out, int out_size, void* d_ws, size_t ws_size,
                              hipStream_t stream) {
  const float* p     = (const float*)d_in[0];
  const float* queue = (const float*)d_in[1];
  const float* maskp = (const float*)d_in[2];
  const int*   label = (const int*)d_in[3];
  float* out = (float*)d_out;
  char* ws = (char*)d_ws;

  unsigned short* pbf  = (unsigned short*)(ws + WS_PBF);
  unsigned short* qbf0 = (unsigned short*)(ws + WS_QBF0);
  unsigned short* wbf  = (unsigned short*)(ws + WS_WBF);

  hipMemsetAsync(ws, 0, 16, stream);  // zero the atomic accumulators

  cvt_all<<<Q_ / 4 + B_ / 4, 256, 0, stream>>>(queue, p, maskp, qbf0, wbf, pbf);

  dim3 g1(NSPLIT, B_ / MT);   // (64, 8): x=split -> XCD=split%8; all 512 resident
  fused_gemm_partial<<<g1, 256, 0, stream>>>(pbf, qbf0, wbf, maskp, label, ws);
  finalize_rows<<<B_, 128, 0, stream>>>(p, queue, maskp, label, ws);
  finalize_scalar<<<1, 1, 0, stream>>>(ws, out);
}

// Round 5
// 594.853 us; speedup vs baseline: 1.2334x; 1.2334x over previous
//
#include <hip/hip_runtime.h>
#include <stdint.h>

#define B_ 1024
#define Q_ 65536
#define D_ 512
#define MT 128
#define NT 128
#define BK 64
#define NSPLIT 64
#define NCHUNK (Q_ / NSPLIT)   // 1024
#define NTILES (NCHUNK / NT)   // 8
#define KITERS (D_ / BK)       // 8

#define SCALE32 32.0f
#define C32 46.16624130844683f   // 32 * log2(e)

// ---- workspace layout (bytes) ----
// [0,32)   : ce_acc f32 | neg_acc f32 | npos i32 | nneg i32 | done i32 | pad
// [4 KB)   : LSE partials float2(Z_mat0, Z_mat1), idx row*64+split  (512 KB)
// [1 MB)   : top-10 partials, idx ((mat*B+row)*64+split)*10         (5.24 MB)
// [8 MB)   : p bf16 (1 MB)
// [12 MB)  : queue[0] bf16 (64 MB)
// [76 MB)  : w = m*q1+(1-m)*q0 bf16, written only where mask!=0 (64 MB region)
#define WS_ACC  0
#define WS_LSE  4096
#define WS_TOPK (1u * 1024u * 1024u)
#define WS_PBF  (8u * 1024u * 1024u)
#define WS_QBF0 (12u * 1024u * 1024u)
#define WS_WBF  (76u * 1024u * 1024u)

// ---- LDS: staging sA[0,16K) sB0[16K,32K) sB1[32K,48K); 16B-XOR swizzle.
// topk compact (2 mats x 32 rows x 128 cols bf16 = 16 KB) aliases sA.
#define SA_OFF 0
#define SB0_OFF 16384
#define SB1_OFF 32768

typedef __attribute__((ext_vector_type(8))) short short8;
typedef __attribute__((ext_vector_type(4))) short short4v;
typedef __attribute__((ext_vector_type(4))) float f32x4;

__device__ __forceinline__ unsigned short f2bf(float x) {
  union { float f; uint32_t u; } v; v.f = x;
  uint32_t r = v.u + 0x7fffu + ((v.u >> 16) & 1u);   // RNE
  return (unsigned short)(r >> 16);
}

__device__ __forceinline__ float bf2f(short u) {
  union { uint32_t i; float f; } v;
  v.i = ((uint32_t)(unsigned short)u) << 16;
  return v.f;
}

__device__ __forceinline__ void async16(void* lds, const void* g) {
  void* gg = (void*)g;
  __builtin_amdgcn_global_load_lds(
      (__attribute__((address_space(1))) unsigned int*)gg,
      (__attribute__((address_space(3))) unsigned int*)lds,
      16, 0, 0);
}

__device__ __forceinline__ void tkins(float v,
    float& t0, float& t1, float& t2, float& t3, float& t4,
    float& t5, float& t6, float& t7, float& t8, float& t9) {
  if (v > t9) {
    t9 = (v > t8) ? t8 : v;
    t8 = (v > t8) ? ((v > t7) ? t7 : v) : t8;
    t7 = (v > t7) ? ((v > t6) ? t6 : v) : t7;
    t6 = (v > t6) ? ((v > t5) ? t5 : v) : t6;
    t5 = (v > t5) ? ((v > t4) ? t4 : v) : t5;
    t4 = (v > t4) ? ((v > t3) ? t3 : v) : t4;
    t3 = (v > t3) ? ((v > t2) ? t2 : v) : t3;
    t2 = (v > t2) ? ((v > t1) ? t1 : v) : t2;
    t1 = (v > t1) ? ((v > t0) ? t0 : v) : t1;
    t0 = (v > t0) ? v : t0;
  }
}

#define TKA(v, a) tkins((v), a[0], a[1], a[2], a[3], a[4], a[5], a[6], a[7], a[8], a[9])

// fused converter: queue fp32 -> qbf0 always; wbf only where mask!=0; p -> pbf
__global__ void cvt_all(const float* __restrict__ q, const float* __restrict__ p,
                        const float* __restrict__ mask,
                        unsigned short* __restrict__ qbf0,
                        unsigned short* __restrict__ wbf,
                        unsigned short* __restrict__ pbf) {
  const int wv = threadIdx.x >> 6;
  const int lane = threadIdx.x & 63;
  const int b = blockIdx.x;
  if (b < Q_ / 4) {
    const int row = b * 4 + wv;
    const float* q0r = q + (size_t)row * D_ + lane * 8;
    float4 a = ((const float4*)q0r)[0];
    float4 bb = ((const float4*)q0r)[1];
    short8 o;
    o[0] = (short)f2bf(a.x); o[1] = (short)f2bf(a.y);
    o[2] = (short)f2bf(a.z); o[3] = (short)f2bf(a.w);
    o[4] = (short)f2bf(bb.x); o[5] = (short)f2bf(bb.y);
    o[6] = (short)f2bf(bb.z); o[7] = (short)f2bf(bb.w);
    *(short8*)(qbf0 + (size_t)row * D_ + lane * 8) = o;
    float m = mask[row];
    if (m != 0.0f) {      // wave-uniform; ~10% of rows
      const float* q1r = q0r + (size_t)Q_ * D_;
      float4 c = ((const float4*)q1r)[0];
      float4 d = ((const float4*)q1r)[1];
      a.x = fmaf(m, c.x - a.x, a.x); a.y = fmaf(m, c.y - a.y, a.y);
      a.z = fmaf(m, c.z - a.z, a.z); a.w = fmaf(m, c.w - a.w, a.w);
      bb.x = fmaf(m, d.x - bb.x, bb.x); bb.y = fmaf(m, d.y - bb.y, bb.y);
      bb.z = fmaf(m, d.z - bb.z, bb.z); bb.w = fmaf(m, d.w - bb.w, bb.w);
      o[0] = (short)f2bf(a.x); o[1] = (short)f2bf(a.y);
      o[2] = (short)f2bf(a.z); o[3] = (short)f2bf(a.w);
      o[4] = (short)f2bf(bb.x); o[5] = (short)f2bf(bb.y);
      o[6] = (short)f2bf(bb.z); o[7] = (short)f2bf(bb.w);
      *(short8*)(wbf + (size_t)row * D_ + lane * 8) = o;
    }
  } else {
    const int row = (b - Q_ / 4) * 4 + wv;
    const float* pr = p + (size_t)row * D_ + lane * 8;
    float4 a = ((const float4*)pr)[0];
    float4 bb = ((const float4*)pr)[1];
    short8 o;
    o[0] = (short)f2bf(a.x); o[1] = (short)f2bf(a.y);
    o[2] = (short)f2bf(a.z); o[3] = (short)f2bf(a.w);
    o[4] = (short)f2bf(bb.x); o[5] = (short)f2bf(bb.y);
    o[6] = (short)f2bf(bb.z); o[7] = (short)f2bf(bb.w);
    *(short8*)(pbf + (size_t)row * D_ + lane * 8) = o;
  }
}

// grid (64, 8): x=split -> XCD=split%8, all 512 blocks co-resident (2/CU).
// Dual-GEMM per block. Z epilogue: register exps -> lr-shuffle-reduce -> LDS
// accumulate (fixed M=32, no running max). Top-10 only for outlier rows via
// 16 KB LDS compaction; owner threads keep top-10 in registers across nt.
__global__ __launch_bounds__(256, 2) void fused_gemm_partial(
    const unsigned short* __restrict__ pbf,
    const unsigned short* __restrict__ qbf0,
    const unsigned short* __restrict__ wbf,
    const float* __restrict__ maskp,
    const int* __restrict__ label,
    char* __restrict__ ws) {
  __shared__ __align__(16) unsigned char smem[49152];
  __shared__ float maskb[NT];
  __shared__ float zacc[MT][4];      // [row][wc*2+mat], accumulated across nt
  __shared__ int olist[MT];
  __shared__ int rowmap[MT];
  __shared__ int sh_ocount;

  const int tid = threadIdx.x;
  const int split = blockIdx.x;       // 0..63
  const int mblk = blockIdx.y;        // 0..7
  const int lane = tid & 63;
  const int wv = tid >> 6;
  const int wr = wv >> 1;
  const int wc = wv & 1;
  const int lr = lane & 15;
  const int lg = lane >> 4;

  if (tid == 0) sh_ocount = 0;
  if (tid < MT) {
    rowmap[tid] = -1;
    zacc[tid][0] = 0.0f; zacc[tid][1] = 0.0f;
    zacc[tid][2] = 0.0f; zacc[tid][3] = 0.0f;
  }
  __syncthreads();
  if (tid < MT) {
    if (label[mblk * MT + tid] == -1) {
      int k = atomicAdd(&sh_ocount, 1);
      olist[k] = tid;
    }
  }
  __syncthreads();
  const int noc = sh_ocount;
  if (tid < noc) rowmap[olist[tid]] = tid;
  __syncthreads();
  const int nchunks = (noc + 31) >> 5;

  // staging lane constants: lane covers row slot*8+(lane>>3),
  // swizzled col16 = (lane&7) ^ (row&7)
  const int srow = lane >> 3;
  const int sc16 = (lane & 7) ^ srow;
  const size_t g_lane_off = (size_t)srow * D_ + sc16 * 8;

  // owner top-10 (only threads with tid&3==0 and pair<64 use it)
  float T[10];
#pragma unroll
  for (int i = 0; i < 10; ++i) T[i] = -1e30f;

  for (int nt = 0; nt < NTILES; ++nt) {
    const int nbase = split * NCHUNK + nt * NT;
    if (tid < NT) maskb[tid] = maskp[nbase + tid];
    __syncthreads();   // maskb ready; also fences smem reuse from prev nt scan

    // per-slot B1 source select (mask==0 rows read qbf0 -> L2-hot after B0)
    const unsigned short* b1b[4];
#pragma unroll
    for (int t = 0; t < 4; ++t) {
      const int rowl = (wv * 4 + t) * 8 + srow;
      b1b[t] = (maskb[rowl] != 0.0f) ? wbf : qbf0;
    }

    f32x4 acc0[4][4], acc1[4][4];
#pragma unroll
    for (int i = 0; i < 4; ++i)
#pragma unroll
      for (int j = 0; j < 4; ++j) {
        f32x4 z = {0.0f, 0.0f, 0.0f, 0.0f};
        acc0[i][j] = z;
        acc1[i][j] = z;
      }

    for (int kk = 0; kk < KITERS; ++kk) {
      const size_t kcol = (size_t)kk * BK;
#pragma unroll
      for (int t = 0; t < 4; ++t) {
        const int slot = wv * 4 + t;
        const size_t rbase = (size_t)slot * 8;
        async16(smem + SA_OFF + slot * 1024,
                pbf + ((size_t)mblk * MT + rbase) * D_ + kcol + g_lane_off);
        async16(smem + SB0_OFF + slot * 1024,
                qbf0 + ((size_t)nbase + rbase) * D_ + kcol + g_lane_off);
        async16(smem + SB1_OFF + slot * 1024,
                b1b[t] + ((size_t)nbase + rbase) * D_ + kcol + g_lane_off);
      }
      __syncthreads();

#pragma unroll
      for (int s = 0; s < 2; ++s) {
        const int xs = ((s * 4 + lg) ^ (lr & 7)) * 16;
        short8 af[4], bf[4];
#pragma unroll
        for (int i = 0; i < 4; ++i)
          af[i] = *(const short8*)(smem + SA_OFF + (wr * 64 + i * 16 + lr) * 128 + xs);
#pragma unroll
        for (int j = 0; j < 4; ++j)
          bf[j] = *(const short8*)(smem + SB0_OFF + (wc * 64 + j * 16 + lr) * 128 + xs);
#pragma unroll
        for (int i = 0; i < 4; ++i)
#pragma unroll
          for (int j = 0; j < 4; ++j)
            acc0[i][j] = __builtin_amdgcn_mfma_f32_16x16x32_bf16(af[i], bf[j], acc0[i][j], 0, 0, 0);
#pragma unroll
        for (int j = 0; j < 4; ++j)
          bf[j] = *(const short8*)(smem + SB1_OFF + (wc * 64 + j * 16 + lr) * 128 + xs);
#pragma unroll
        for (int i = 0; i < 4; ++i)
#pragma unroll
          for (int j = 0; j < 4; ++j)
            acc1[i][j] = __builtin_amdgcn_mfma_f32_16x16x32_bf16(af[i], bf[j], acc1[i][j], 0, 0, 0);
      }
      __syncthreads();
    }

    // ---- Z epilogue: exps in regs, lr-shuffle reduce, LDS accumulate ----
#pragma unroll
    for (int i = 0; i < 4; ++i)
#pragma unroll
      for (int k = 0; k < 4; ++k) {
        float a0 = 0.0f, a1 = 0.0f;
#pragma unroll
        for (int j = 0; j < 4; ++j) {
          a0 += __builtin_amdgcn_exp2f(fmaf(acc0[i][j][k], C32, -C32));
          a1 += __builtin_amdgcn_exp2f(fmaf(acc1[i][j][k], C32, -C32));
        }
#pragma unroll
        for (int m = 1; m < 16; m <<= 1) {
          a0 += __shfl_xor(a0, m, 64);
          a1 += __shfl_xor(a1, m, 64);
        }
        if (lr == 0) {
          const int r = wr * 64 + i * 16 + lg * 4 + k;
          zacc[r][wc * 2 + 0] += a0;
          zacc[r][wc * 2 + 1] += a1;
        }
      }

    // ---- top-10 for outlier rows: LDS compact -> 4-thread scans -> merge ----
    for (int c = 0; c < nchunks; ++c) {
      unsigned short* cp = (unsigned short*)smem;   // aliases sA (16 KB)
#pragma unroll
      for (int i = 0; i < 4; ++i)
#pragma unroll
        for (int k = 0; k < 4; ++k) {
          const int r = wr * 64 + i * 16 + lg * 4 + k;
          const int o = rowmap[r];
          const int ol = o - c * 32;
          if (o >= 0 && ol >= 0 && ol < 32) {
#pragma unroll
            for (int j = 0; j < 4; ++j) {
              const int col = wc * 64 + j * 16 + lr;
              cp[ol * 128 + col] = f2bf(acc0[i][j][k]);
              cp[(32 + ol) * 128 + col] = f2bf(acc1[i][j][k]);
            }
          }
        }
      __syncthreads();

      {
        float tl[10];
#pragma unroll
        for (int r = 0; r < 10; ++r) tl[r] = -1e30f;
        const int pair = tid >> 2;      // 0..63: (orow, mat)
        const int q4 = tid & 3;
        const int orow = pair >> 1, mat = pair & 1;
        const int o = c * 32 + orow;
        if (o < noc) {
          const unsigned short* rp = cp + (mat * 32 + orow) * 128 + q4 * 32;
#pragma unroll
          for (int cc = 0; cc < 8; ++cc) {
            short4v v = *(const short4v*)(rp + cc * 4);
            TKA(bf2f(v.x), tl); TKA(bf2f(v.y), tl);
            TKA(bf2f(v.z), tl); TKA(bf2f(v.w), tl);
          }
          // merge across the 4 quarter-threads (same wave: xor 1 then 2)
          float ot[10];
#pragma unroll
          for (int r = 0; r < 10; ++r) ot[r] = __shfl_xor(tl[r], 1, 64);
#pragma unroll
          for (int r = 0; r < 10; ++r) TKA(ot[r], tl);
#pragma unroll
          for (int r = 0; r < 10; ++r) ot[r] = __shfl_xor(tl[r], 2, 64);
#pragma unroll
          for (int r = 0; r < 10; ++r) TKA(ot[r], tl);
          if (q4 == 0) {
            if (c == 0) {
#pragma unroll
              for (int r = 0; r < 10; ++r) TKA(tl[r], T);
            } else {
              // rare overflow path (noc > 32): RMW ws slot per nt
              float* slot = (float*)(ws + WS_TOPK) +
                  ((size_t)(mat * B_ + mblk * MT + olist[o]) * NSPLIT + split) * 10;
              if (nt == 0) {
#pragma unroll
                for (int r = 0; r < 10; ++r) slot[r] = tl[r];
              } else {
                float cur[10];
#pragma unroll
                for (int r = 0; r < 10; ++r) cur[r] = slot[r];
#pragma unroll
                for (int r = 0; r < 10; ++r) TKA(tl[r], cur);
#pragma unroll
                for (int r = 0; r < 10; ++r) slot[r] = cur[r];
              }
            }
          }
        }
      }
      __syncthreads();
    }
  }

  // ---- block end: write Z partials and owner top-10 lists ----
  if (tid < MT) {
    float2* lseo = (float2*)(ws + WS_LSE);
    lseo[(size_t)(mblk * MT + tid) * NSPLIT + split] =
        make_float2(zacc[tid][0] + zacc[tid][2], zacc[tid][1] + zacc[tid][3]);
  }
  {
    const int pair = tid >> 2;
    const int q4 = tid & 3;
    const int orow = pair >> 1, mat = pair & 1;
    if (q4 == 0 && orow < noc && orow < 32) {
      float* slot = (float*)(ws + WS_TOPK) +
          ((size_t)(mat * B_ + mblk * MT + olist[orow]) * NSPLIT + split) * 10;
#pragma unroll
      for (int r = 0; r < 10; ++r) slot[r] = T[r];
    }
  }
}

__global__ void finalize_rows(
    const float* __restrict__ p, const float* __restrict__ queue,
    const float* __restrict__ maskp, const int* __restrict__ label,
    char* __restrict__ ws, float* __restrict__ out) {
  const int row = blockIdx.x;
  const int l = threadIdx.x >> 6;     // 0: cos1 loss, 1: cos2 loss
  const int lane = threadIdx.x & 63;
  const int lab = label[row];
  float* wsf = (float*)ws;
  int* wsi = (int*)ws;

  if (lab != -1) {
    // ---- sum 64 split Z partials (fixed M=32) ----
    const float2* lsep = (const float2*)(ws + WS_LSE) + (size_t)row * NSPLIT;
    float2 zz = lsep[lane];
    float z = (l == 0) ? zz.x : zz.y;
#pragma unroll
    for (int o = 1; o < 64; o <<= 1) z += __shfl_xor(z, o, 64);

    // ---- exact fp32 gt dot(s) ----
    const float* prow = p + (size_t)row * D_;
    const float* q0r = queue + (size_t)lab * D_;
    const float* q1r = queue + ((size_t)Q_ + (size_t)lab) * D_;
    int c = lane * 8;
    float4 a0 = *(const float4*)(prow + c);
    float4 a1 = *(const float4*)(prow + c + 4);
    float4 b0 = *(const float4*)(q0r + c);
    float4 b1 = *(const float4*)(q0r + c + 4);
    float d0 = a0.x * b0.x + a0.y * b0.y + a0.z * b0.z + a0.w * b0.w
             + a1.x * b1.x + a1.y * b1.y + a1.z * b1.z + a1.w * b1.w;
    float d1 = 0.0f;
    if (l == 1) {
      float4 c0 = *(const float4*)(q1r + c);
      float4 c1 = *(const float4*)(q1r + c + 4);
      d1 = a0.x * c0.x + a0.y * c0.y + a0.z * c0.z + a0.w * c0.w
         + a1.x * c1.x + a1.y * c1.y + a1.z * c1.z + a1.w * c1.w;
    }
#pragma unroll
    for (int o = 1; o < 64; o <<= 1) {
      d0 += __shfl_xor(d0, o, 64);
      d1 += __shfl_xor(d1, o, 64);
    }
    float gt;
    if (l == 0) gt = d0;
    else { float m = maskp[lab]; gt = fmaf(m, d1 - d0, d0); }

    if (lane == 0) {
      float e1 = __builtin_amdgcn_exp2f(fmaf(gt, C32, -C32));
      float e2 = __builtin_amdgcn_exp2f(fmaf(gt - 0.4f, C32, -C32));
      float Zc = z - e1 + e2;
      float ce = 32.0f + __logf(Zc) - (gt - 0.4f) * SCALE32;
      atomicAdd(&wsf[0], ce);
      if (l == 0) atomicAdd(&wsi[2], 1);
    }
  } else {
    // ---- merge 64 sorted top-10 lists: 10-round wave tournament ----
    const float* tp = (const float*)(ws + WS_TOPK) +
                      ((size_t)l * B_ + row) * NSPLIT * 10 + (size_t)lane * 10;
    float t0 = tp[0], t1 = tp[1], t2 = tp[2], t3 = tp[3], t4 = tp[4];
    float t5 = tp[5], t6 = tp[6], t7 = tp[7], t8 = tp[8], t9 = tp[9];
    float ssum = 0.0f;
#pragma unroll
    for (int r10 = 0; r10 < 10; ++r10) {
      float v = t0;
      int idx = lane;
#pragma unroll
      for (int o = 1; o < 64; o <<= 1) {
        float ov = __shfl_xor(v, o, 64);
        int oi = __shfl_xor(idx, o, 64);
        bool take = (ov > v) || (ov == v && oi < idx);
        v = take ? ov : v;
        idx = take ? oi : idx;
      }
      ssum += fmaxf(v, 0.0f);
      if (idx == lane) {
        t0 = t1; t1 = t2; t2 = t3; t3 = t4; t4 = t5;
        t5 = t6; t6 = t7; t7 = t8; t8 = t9; t9 = -1e30f;
      }
    }
    if (lane == 0) {
      atomicAdd(&wsf[1], ssum * 0.1f);
      if (l == 0) atomicAdd(&wsi[3], 1);
    }
  }

  // ---- last block computes the final scalar (saves a launch) ----
  __syncthreads();
  if (threadIdx.x == 0) {
    __threadfence();
    int old = atomicAdd(&wsi[4], 1);
    if (old == B_ - 1) {
      float ce = atomicAdd(&wsf[0], 0.0f);   // coherent reads
      float ng = atomicAdd(&wsf[1], 0.0f);
      int np = atomicAdd(&wsi[2], 0);
      int nn = atomicAdd(&wsi[3], 0);
      float loss = 0.0f;
      if (np > 0) loss += ce / (float)np;
      if (nn > 0) loss += ng / (float)nn;
      out[0] = loss;
    }
  }
}

extern "C" void kernel_launch(void* const* d_in, const int* in_sizes, int n_in,
                              void* d_out, int out_size, void* d_ws, size_t ws_size,
                              hipStream_t stream) {
  const float* p     = (const float*)d_in[0];
  const float* queue = (const float*)d_in[1];
  const float* maskp = (const float*)d_in[2];
  const int*   label = (const int*)d_in[3];
  float* out = (float*)d_out;
  char* ws = (char*)d_ws;

  unsigned short* pbf  = (unsigned short*)(ws + WS_PBF);
  unsigned short* qbf0 = (unsigned short*)(ws + WS_QBF0);
  unsigned short* wbf  = (unsigned short*)(ws + WS_WBF);

  hipMemsetAsync(ws, 0, 32, stream);  // zero the accumulators + done counter

  cvt_all<<<Q_ / 4 + B_ / 4, 256, 0, stream>>>(queue, p, maskp, qbf0, wbf, pbf);

  dim3 g1(NSPLIT, B_ / MT);   // (64, 8): x=split -> XCD=split%8; all 512 resident
  fused_gemm_partial<<<g1, 256, 0, stream>>>(pbf, qbf0, wbf, maskp, label, ws);
  finalize_rows<<<B_, 128, 0, stream>>>(p, queue, maskp, label, ws, out);
}